// Round 2
// baseline (45.654 us; speedup 1.0000x reference)
//
#include <hip/hip_runtime.h>

#define B   4
#define N   1024
#define F   128
#define HID 64
#define EMB 32
#define NIC 128         // i-chunks
#define IC  (N/NIC)     // 8 rows of i per chunk
#define JB  256         // j per block
#define NCH (NIC*4)     // chunks per batch in out_part (NIC * n_jblk)

// ---------------- Kernel 1: per-row MLP -> e, a_i, a_j ----------------
// One wave per row r in [0, B*N). 4 waves / block.
__global__ __launch_bounds__(256) void k1_embed(
    const float* __restrict__ x,  const float* __restrict__ W1, const float* __restrict__ b1,
    const float* __restrict__ W2, const float* __restrict__ b2,
    const float* __restrict__ Wa1,
    float* __restrict__ e, float* __restrict__ ai, float* __restrict__ aj)
{
    __shared__ float sh_x[4][F];
    __shared__ float sh_h[4][HID];
    __shared__ float sh_e[4][EMB];
    const int tid  = threadIdx.x;
    const int w    = tid >> 6;
    const int lane = tid & 63;
    const int r    = blockIdx.x * 4 + w;

    // stage x row into LDS (broadcast source for the dot products)
    sh_x[w][lane]      = x[(size_t)r * F + lane];
    sh_x[w][lane + 64] = x[(size_t)r * F + 64 + lane];
    __syncthreads();

    // h[lane] = relu(x_row . W1[:,lane] + b1[lane])
    float acc = b1[lane];
    #pragma unroll 16
    for (int k = 0; k < F; ++k)
        acc = fmaf(sh_x[w][k], W1[k * HID + lane], acc);
    sh_h[w][lane] = fmaxf(acc, 0.f);
    __syncthreads();

    // e[d] = h . W2[:,d] + b2[d]   (all lanes compute, lanes<32 write)
    const int d = lane & 31;
    float ev = b2[d];
    #pragma unroll 16
    for (int k = 0; k < HID; ++k)
        ev = fmaf(sh_h[w][k], W2[k * EMB + d], ev);
    if (lane < EMB) {
        sh_e[w][d] = ev;
        e[(size_t)r * EMB + d] = ev;
    }
    __syncthreads();

    // lanes 0..31 -> a_i[d] = e . Wa1[:EMB][:,d];  lanes 32..63 -> a_j via Wa1[EMB:]
    const float* Wp = Wa1 + (lane < 32 ? 0 : EMB * EMB);
    float av = 0.f;
    #pragma unroll 16
    for (int k = 0; k < EMB; ++k)
        av = fmaf(sh_e[w][k], Wp[k * EMB + d], av);
    if (lane < 32) ai[(size_t)r * EMB + d] = av;
    else           aj[(size_t)r * EMB + d] = av;
}

// ---------------- Kernel 2: fused attention + e-weighted block reduce ------
// block = 256 threads (one j each); grid = (NIC, B*4)
// out_part[b, ic*4+jblk, d] = sum_{j in block} (sum_{i in chunk} att[i,j]) * e[b,j,d]
__global__ __launch_bounds__(256) void k2_att(
    const float* __restrict__ ai, const float* __restrict__ aj,
    const float* __restrict__ ba1, const float* __restrict__ Wa2,
    const float* __restrict__ ba2, const float* __restrict__ adj,
    const float* __restrict__ e, float* __restrict__ out_part)
{
    const int ic   = blockIdx.x;          // 0..NIC-1
    const int b    = blockIdx.y >> 2;
    const int jblk = blockIdx.y & 3;
    const int tid  = threadIdx.x;
    const int j    = jblk * JB + tid;
    const int i0   = ic * IC;

    __shared__ float4 sh_ai[IC][EMB / 4];   // 8 rows x 8 float4 = 1 KiB
    if (tid < IC * (EMB / 4)) {             // 64 threads stage one float4 each
        const int row = tid >> 3, c4 = tid & 7;
        sh_ai[row][c4] =
            ((const float4*)(ai + ((size_t)b * N + i0 + row) * EMB))[c4];
    }

    // per-thread a_j + ba1 in registers (vector loads)
    float ajb[EMB];
    {
        const float4* ap = (const float4*)(aj + ((size_t)b * N + j) * EMB);
        const float4* bp = (const float4*)ba1;
        #pragma unroll
        for (int q = 0; q < EMB / 4; ++q) {
            const float4 a4 = ap[q], b4 = bp[q];
            ajb[4 * q + 0] = a4.x + b4.x;
            ajb[4 * q + 1] = a4.y + b4.y;
            ajb[4 * q + 2] = a4.z + b4.z;
            ajb[4 * q + 3] = a4.w + b4.w;
        }
    }
    // uniform weights -> scalar regs
    float w2[EMB];
    #pragma unroll
    for (int d2 = 0; d2 < EMB; ++d2) w2[d2] = Wa2[d2];
    const float bb = ba2[0];

    // prefetch the whole adj column slice for this chunk (independent loads)
    float adjv[IC];
    {
        const float* adjp = adj + (size_t)i0 * N + j;
        #pragma unroll
        for (int i = 0; i < IC; ++i) adjv[i] = adjp[(size_t)i * N];
    }
    __syncthreads();

    float ssum = 0.f;
    #pragma unroll
    for (int i = 0; i < IC; ++i) {
        const float4* arow = sh_ai[i];
        float acc0 = bb, acc1 = 0.f, acc2 = 0.f, acc3 = 0.f;
        #pragma unroll
        for (int q = 0; q < EMB / 4; ++q) {
            const float4 a4 = arow[q];
            acc0 = fmaf(fmaxf(a4.x + ajb[4 * q + 0], 0.f), w2[4 * q + 0], acc0);
            acc1 = fmaf(fmaxf(a4.y + ajb[4 * q + 1], 0.f), w2[4 * q + 1], acc1);
            acc2 = fmaf(fmaxf(a4.z + ajb[4 * q + 2], 0.f), w2[4 * q + 2], acc2);
            acc3 = fmaf(fmaxf(a4.w + ajb[4 * q + 3], 0.f), w2[4 * q + 3], acc3);
        }
        const float dot = (acc0 + acc1) + (acc2 + acc3);
        const float sg  = __builtin_amdgcn_rcpf(1.f + __expf(-dot));  // sigmoid
        ssum = fmaf(sg, adjv[i], ssum);
    }

    // ---- block tail: out_part[d] = sum_j ssum_j * e[b,j,d] ----
    __shared__ float sh_s[JB];
    sh_s[tid] = ssum;
    __syncthreads();

    const int d = tid & 31, g = tid >> 5;           // 8 j-groups of 32
    const float* ep = e + ((size_t)b * N + jblk * JB + g * 32) * EMB + d;
    float pacc = 0.f;
    #pragma unroll
    for (int jj = 0; jj < 32; ++jj)
        pacc = fmaf(sh_s[g * 32 + jj], ep[(size_t)jj * EMB], pacc);

    __shared__ float sh_r[8][EMB];
    sh_r[g][d] = pacc;
    __syncthreads();
    if (tid < EMB) {
        float s = 0.f;
        #pragma unroll
        for (int t = 0; t < 8; ++t) s += sh_r[t][tid];
        out_part[((size_t)b * NCH + ic * 4 + jblk) * EMB + tid] = s;
    }
}

// ---------------- Kernel 3: out[b,d] = (1/N) * sum_c out_part[b,c,d] -------
__global__ __launch_bounds__(256) void k3_out(
    const float* __restrict__ out_part, float* __restrict__ out)
{
    const int b   = blockIdx.x;
    const int tid = threadIdx.x;
    const int d = tid & 31, g = tid >> 5;
    float acc = 0.f;
    for (int c = g; c < NCH; c += 8)
        acc += out_part[((size_t)b * NCH + c) * EMB + d];
    __shared__ float sh[8][EMB];
    sh[g][d] = acc;
    __syncthreads();
    if (tid < EMB) {
        float s = 0.f;
        #pragma unroll
        for (int t = 0; t < 8; ++t) s += sh[t][tid];
        out[b * EMB + tid] = s * (1.0f / N);
    }
}

// ---------------------------------------------------------------------------
extern "C" void kernel_launch(void* const* d_in, const int* in_sizes, int n_in,
                              void* d_out, int out_size, void* d_ws, size_t ws_size,
                              hipStream_t stream) {
    const float* x    = (const float*)d_in[0];
    const float* adj  = (const float*)d_in[1];
    const float* W1   = (const float*)d_in[2];
    const float* b1   = (const float*)d_in[3];
    const float* W2   = (const float*)d_in[4];
    const float* b2   = (const float*)d_in[5];
    const float* Wa1  = (const float*)d_in[6];
    const float* ba1  = (const float*)d_in[7];
    const float* Wa2  = (const float*)d_in[8];
    const float* ba2  = (const float*)d_in[9];
    float* out = (float*)d_out;

    float* ws = (float*)d_ws;
    float* e        = ws;                 // B*N*EMB   = 131072
    float* ai       = ws + 131072;        // 131072
    float* aj       = ws + 262144;        // 131072
    float* out_part = ws + 393216;        // B*NCH*EMB = 65536

    k1_embed<<<(B * N) / 4, 256, 0, stream>>>(x, W1, b1, W2, b2, Wa1, e, ai, aj);
    k2_att<<<dim3(NIC, B * 4), 256, 0, stream>>>(ai, aj, ba1, Wa2, ba2, adj, e, out_part);
    k3_out<<<B, 256, 0, stream>>>(out_part, out);
}

// Round 3
// 41.091 us; speedup vs baseline: 1.1110x; 1.1110x over previous
//
#include <hip/hip_runtime.h>

#define B   4
#define N   1024
#define F   128
#define HID 64
#define EMB 32
#define NIS 32          // i-splits for k2
#define IC2 (N/NIS)     // 32 i-rows per block
#define JB  256         // j per block
#define NCH (NIS*4)     // partial chunks per batch

// ---------------- Kernel 1: per-row MLP -> e, a_i, a_j ----------------
__global__ __launch_bounds__(256, 4) void k1_embed(
    const float* __restrict__ x,  const float* __restrict__ W1, const float* __restrict__ b1,
    const float* __restrict__ W2, const float* __restrict__ b2,
    const float* __restrict__ Wa1,
    float* __restrict__ e, float* __restrict__ ai, float* __restrict__ aj)
{
    __shared__ float sh_x[4][F];
    __shared__ float sh_h[4][HID];
    __shared__ float sh_e[4][EMB];
    const int tid  = threadIdx.x;
    const int w    = tid >> 6;
    const int lane = tid & 63;
    const int r    = blockIdx.x * 4 + w;

    sh_x[w][lane]      = x[(size_t)r * F + lane];
    sh_x[w][lane + 64] = x[(size_t)r * F + 64 + lane];
    __syncthreads();

    // h[lane] = relu(x . W1[:,lane] + b1[lane]) — two chains for ILP
    float acc0 = b1[lane], acc1 = 0.f;
    #pragma unroll 8
    for (int k = 0; k < F; k += 2) {
        acc0 = fmaf(sh_x[w][k],     W1[k * HID + lane],       acc0);
        acc1 = fmaf(sh_x[w][k + 1], W1[(k + 1) * HID + lane], acc1);
    }
    sh_h[w][lane] = fmaxf(acc0 + acc1, 0.f);
    __syncthreads();

    const int d = lane & 31;
    float ev = b2[d];
    #pragma unroll 8
    for (int k = 0; k < HID; ++k)
        ev = fmaf(sh_h[w][k], W2[k * EMB + d], ev);
    if (lane < EMB) {
        sh_e[w][d] = ev;
        e[(size_t)r * EMB + d] = ev;
    }
    __syncthreads();

    const float* Wp = Wa1 + (lane < 32 ? 0 : EMB * EMB);
    float av = 0.f;
    #pragma unroll 8
    for (int k = 0; k < EMB; ++k)
        av = fmaf(sh_e[w][k], Wp[k * EMB + d], av);
    if (lane < 32) ai[(size_t)r * EMB + d] = av;
    else           aj[(size_t)r * EMB + d] = av;
}

// ---------------- Kernel 2: fused attention + e-weighted block reduce ------
// grid (NIS, B*4); block 256 (one j per thread)
// out_part[b, ic*4+jblk, d] = sum_{j in jblk} (sum_{i in chunk} att[i,j]) * e[b,j,d]
#define LOADCH(av, t)                                    \
    av[0] = adjp[(size_t)((t) * 4 + 0) * N];             \
    av[1] = adjp[(size_t)((t) * 4 + 1) * N];             \
    av[2] = adjp[(size_t)((t) * 4 + 2) * N];             \
    av[3] = adjp[(size_t)((t) * 4 + 3) * N];

#define COMPCH(av, t) do {                                                     \
    _Pragma("unroll")                                                          \
    for (int u = 0; u < 4; ++u) {                                              \
        const float4* arow = sh_ai[(t) * 4 + u];                               \
        float c0 = bb, c1 = 0.f, c2 = 0.f, c3 = 0.f;                           \
        _Pragma("unroll")                                                      \
        for (int q = 0; q < 8; ++q) {                                          \
            const float4 a4 = arow[q];                                         \
            c0 = fmaf(fmaxf(a4.x + ajb[4 * q + 0], 0.f), w2[4 * q + 0], c0);   \
            c1 = fmaf(fmaxf(a4.y + ajb[4 * q + 1], 0.f), w2[4 * q + 1], c1);   \
            c2 = fmaf(fmaxf(a4.z + ajb[4 * q + 2], 0.f), w2[4 * q + 2], c2);   \
            c3 = fmaf(fmaxf(a4.w + ajb[4 * q + 3], 0.f), w2[4 * q + 3], c3);   \
        }                                                                      \
        const float dt = (c0 + c1) + (c2 + c3);                                \
        const float sg = __builtin_amdgcn_rcpf(1.f + __expf(-dt));             \
        ssum = fmaf(sg, av[u], ssum);                                          \
    } } while (0)

__global__ __launch_bounds__(256, 4) void k2_att(
    const float* __restrict__ ai, const float* __restrict__ aj,
    const float* __restrict__ ba1, const float* __restrict__ Wa2,
    const float* __restrict__ ba2, const float* __restrict__ adj,
    const float* __restrict__ e, float* __restrict__ out_part)
{
    const int ic   = blockIdx.x;          // 0..NIS-1
    const int b    = blockIdx.y >> 2;
    const int jblk = blockIdx.y & 3;
    const int tid  = threadIdx.x;
    const int j    = jblk * JB + tid;
    const int i0   = ic * IC2;

    __shared__ float4 sh_ai[IC2][EMB / 4];   // 32 rows x 8 float4 = 4 KiB
    {   // 256 threads stage exactly one float4 each
        const int row = tid >> 3, c4 = tid & 7;
        sh_ai[row][c4] =
            ((const float4*)(ai + ((size_t)b * N + i0 + row) * EMB))[c4];
    }

    float ajb[EMB];                          // a_j + ba1 (per-thread)
    {
        const float4* ap = (const float4*)(aj + ((size_t)b * N + j) * EMB);
        #pragma unroll
        for (int q = 0; q < EMB / 4; ++q) {
            const float4 a4 = ap[q];
            ajb[4 * q + 0] = a4.x + ba1[4 * q + 0];
            ajb[4 * q + 1] = a4.y + ba1[4 * q + 1];
            ajb[4 * q + 2] = a4.z + ba1[4 * q + 2];
            ajb[4 * q + 3] = a4.w + ba1[4 * q + 3];
        }
    }
    float w2[EMB];                           // uniform -> scalar regs
    #pragma unroll
    for (int d2 = 0; d2 < EMB; ++d2) w2[d2] = Wa2[d2];
    const float bb = ba2[0];
    __syncthreads();

    float ssum = 0.f;
    const float* adjp = adj + (size_t)i0 * N + j;
    float avA[4], avB[4];
    // software-pipelined: load chunk t+1 while computing chunk t (all static idx)
    LOADCH(avA, 0);
    LOADCH(avB, 1); COMPCH(avA, 0);
    LOADCH(avA, 2); COMPCH(avB, 1);
    LOADCH(avB, 3); COMPCH(avA, 2);
    LOADCH(avA, 4); COMPCH(avB, 3);
    LOADCH(avB, 5); COMPCH(avA, 4);
    LOADCH(avA, 6); COMPCH(avB, 5);
    LOADCH(avB, 7); COMPCH(avA, 6);
    COMPCH(avB, 7);

    // ---- block tail: out_part[d] = sum_j ssum_j * e[b,j,d] ----
    __shared__ float sh_s[JB];
    sh_s[tid] = ssum;
    __syncthreads();

    const int d = tid & 31, g = tid >> 5;    // 8 j-groups of 32
    const float* ep = e + ((size_t)b * N + jblk * JB + g * 32) * EMB + d;
    float pacc = 0.f;
    #pragma unroll
    for (int jj = 0; jj < 32; ++jj)
        pacc = fmaf(sh_s[g * 32 + jj], ep[(size_t)jj * EMB], pacc);

    __shared__ float sh_r[8][EMB];
    sh_r[g][d] = pacc;
    __syncthreads();
    if (tid < EMB) {
        float s = 0.f;
        #pragma unroll
        for (int t = 0; t < 8; ++t) s += sh_r[t][tid];
        out_part[((size_t)b * NCH + ic * 4 + jblk) * EMB + tid] = s;
    }
}

// ---------------- Kernel 3: out[b,d] = (1/N) * sum_c out_part[b,c,d] -------
__global__ __launch_bounds__(256) void k3_out(
    const float* __restrict__ out_part, float* __restrict__ out)
{
    const int b   = blockIdx.x;
    const int tid = threadIdx.x;
    const int d4  = tid & 7;                 // which float4 of the 32-dim row
    const int g   = tid >> 3;                // 32 c-groups
    const float4* op = (const float4*)(out_part + (size_t)b * NCH * EMB);

    float4 acc = make_float4(0.f, 0.f, 0.f, 0.f);
    #pragma unroll
    for (int t = 0; t < NCH / 32; ++t) {     // 4 strided reads
        const float4 v = op[(size_t)(g + 32 * t) * (EMB / 4) + d4];
        acc.x += v.x; acc.y += v.y; acc.z += v.z; acc.w += v.w;
    }
    __shared__ float4 sh[32][8];
    sh[g][d4] = acc;
    __syncthreads();
    if (tid < 8) {
        float4 s = make_float4(0.f, 0.f, 0.f, 0.f);
        for (int gg = 0; gg < 32; ++gg) {
            const float4 v = sh[gg][tid];
            s.x += v.x; s.y += v.y; s.z += v.z; s.w += v.w;
        }
        const float inv = 1.0f / N;
        ((float4*)(out + b * EMB))[tid] =
            make_float4(s.x * inv, s.y * inv, s.z * inv, s.w * inv);
    }
}

// ---------------------------------------------------------------------------
extern "C" void kernel_launch(void* const* d_in, const int* in_sizes, int n_in,
                              void* d_out, int out_size, void* d_ws, size_t ws_size,
                              hipStream_t stream) {
    const float* x    = (const float*)d_in[0];
    const float* adj  = (const float*)d_in[1];
    const float* W1   = (const float*)d_in[2];
    const float* b1   = (const float*)d_in[3];
    const float* W2   = (const float*)d_in[4];
    const float* b2   = (const float*)d_in[5];
    const float* Wa1  = (const float*)d_in[6];
    const float* ba1  = (const float*)d_in[7];
    const float* Wa2  = (const float*)d_in[8];
    const float* ba2  = (const float*)d_in[9];
    float* out = (float*)d_out;

    float* ws = (float*)d_ws;
    float* e        = ws;                 // B*N*EMB   = 131072
    float* ai       = ws + 131072;        // 131072
    float* aj       = ws + 262144;        // 131072
    float* out_part = ws + 393216;        // B*NCH*EMB = 16384

    k1_embed<<<(B * N) / 4, 256, 0, stream>>>(x, W1, b1, W2, b2, Wa1, e, ai, aj);
    k2_att<<<dim3(NIS, B * 4), 256, 0, stream>>>(ai, aj, ba1, Wa2, ba2, adj, e, out_part);
    k3_out<<<B, 256, 0, stream>>>(out_part, out);
}